// Round 8
// baseline (141.101 us; speedup 1.0000x reference)
//
#include <hip/hip_runtime.h>
#include <math.h>

#define NT 16384
#define D 4096
#define NE 128
#define NSPLIT 4
#define KS 1024           // K per slice
#define NCH 32            // chunks per slice (BK=32)
#define BMT 128           // tokens per block
#define INV_T (1.0f / 0.07f)
#define TAU 4e-5f
#define FIXCAP 16384

typedef _Float16 h16;
typedef _Float16 h8 __attribute__((ext_vector_type(8)));
typedef _Float16 h4 __attribute__((ext_vector_type(4)));
typedef float f4 __attribute__((ext_vector_type(4)));
typedef float f16v __attribute__((ext_vector_type(16)));

// ---- static device scratch (fully rewritten each call) ----
__device__ float g_S[NSPLIT][NT][NE];    // raw-dot partials (32 MB)
__device__ float g_ssq[NSPLIT][NT];      // |x|^2 partials
__device__ float g_wgn[NE * D];          // normalized W fp32 (fixup)
// W hi-plane packed: [slice][chunk][kh][g][oct][e32][8 h16] -> 8KB per (slice,chunk)
__device__ __align__(16) h16 g_wpk[NE * D];
__device__ int   g_tte[NT];
__device__ int   g_cnt;
__device__ int   g_flag[FIXCAP];
__device__ float g_me[256][NE];
__device__ int   g_hist[256][NE];        // per-64-token-chunk histograms
__device__ int   g_pos[256][NE];

#define GLL(gp, lp) __builtin_amdgcn_global_load_lds( \
    (const __attribute__((address_space(1))) void*)(gp), \
    (__attribute__((address_space(3))) void*)(lp), 16, 0, 0)

// ---------------- kernel 1: normalize W + fp16 hi split + subtile pack --------
__global__ __launch_bounds__(256) void k_prep(const float* __restrict__ wg) {
    int e = blockIdx.x;
    int tid = threadIdx.x;
    if (e == 0 && tid == 0) g_cnt = 0;
    const f4* row = (const f4*)(wg + (size_t)e * D);
    float ss = 0.f;
    f4 v[4];
    #pragma unroll
    for (int c = 0; c < 4; c++) {
        v[c] = row[tid + 256 * c];
        ss += v[c][0]*v[c][0] + v[c][1]*v[c][1] + v[c][2]*v[c][2] + v[c][3]*v[c][3];
    }
    __shared__ float red[4];
    #pragma unroll
    for (int o = 32; o > 0; o >>= 1) ss += __shfl_xor(ss, o, 64);
    if ((tid & 63) == 0) red[tid >> 6] = ss;
    __syncthreads();
    float den = fmaxf(sqrtf(red[0] + red[1] + red[2] + red[3]), 1e-4f);
    int g = e >> 5, e5 = e & 31;
    #pragma unroll
    for (int cc = 0; cc < 4; cc++) {
        int k0 = (tid + 256 * cc) * 4;
        f4 wn;
        h4 hi;
        #pragma unroll
        for (int k = 0; k < 4; k++) {
            wn[k] = v[cc][k] / den;
            hi[k] = (h16)wn[k];
        }
        *(f4*)(g_wgn + (size_t)e * D + k0) = wn;
        // pack: k -> slice=k>>10, kc=(k>>5)&31, kh=(k>>4)&1, oct=(k>>3)&1, d=k&7
        int slice = k0 >> 10, kc = (k0 >> 5) & 31;
        int kh = (k0 >> 4) & 1, oct = (k0 >> 3) & 1;
        size_t off = (size_t)(slice * 32 + kc) * 8192 + (size_t)kh * 4096
                   + (size_t)g * 1024 + (size_t)oct * 512 + (size_t)e5 * 16
                   + (size_t)(k0 & 7) * 2;
        *(h4*)((char*)g_wpk + off) = hi;
    }
}

// ---------------- kernel 2: fp16x2 32x32x16 MFMA split-K GEMM -----------------
// grid 512 = 128 token-blocks x 4 slices; 512 threads = 8 waves -> 2 blk/CU,
// 16 waves/CU (4/SIMD). Wave (wr=w&3, wc=w>>2): 32 tokens x 64 experts.
// Passes: xh*wh + xl*wh (W-lo dropped; error ~4e-6 sigma, tau covers it).
__global__ __launch_bounds__(512, 4) void k_mfma(const float* __restrict__ x) {
    __shared__ __align__(16) char lds[16384];   // 2 x 8KB W double buffer

    const int tid = threadIdx.x;
    const int bid = blockIdx.x;
    const int slice = bid & 3, tb = bid >> 2;
    const int t0 = tb * BMT;
    const int w = tid >> 6, l = tid & 63;
    const int wr = w & 3, wc = w >> 2;
    const int e5 = l & 31, oct = l >> 5;

    const char* wbase = (const char*)g_wpk + (size_t)slice * 32 * 8192 + (size_t)tid * 16;
    // x: row t0 + wr*32 + e5, k = slice*1024 + c*32 + kh*16 + oct*8 + [0,8)
    const float* xb = x + (size_t)(t0 + wr * 32 + e5) * D + slice * KS + oct * 8;
    // ds_read base for this wave's two expert groups
    const int rdo = oct * 512 + e5 * 16;

    f16v acc[2];
    acc[0] = (f16v)0.0f;
    acc[1] = (f16v)0.0f;
    float ssq = 0.f;
    f4 x0[4], x1[4];
    h8 ah[2], al[2];

#define STW(buf, c) GLL(wbase + (size_t)(c) * 8192, lds + (buf) * 8192 + w * 1024)

#define LOADX(X, c) do { \
        X[0] = *(const f4*)(xb + (c) * 32); \
        X[1] = *(const f4*)(xb + (c) * 32 + 4); \
        X[2] = *(const f4*)(xb + (c) * 32 + 16); \
        X[3] = *(const f4*)(xb + (c) * 32 + 20); } while (0)

#define CONVX(X) do { _Pragma("unroll") for (int q = 0; q < 4; q++) { \
        _Pragma("unroll") for (int e2 = 0; e2 < 4; e2++) { \
            float f_ = X[q][e2]; \
            ssq += f_ * f_; \
            h16 h_ = (h16)f_; \
            ah[q >> 1][(q & 1) * 4 + e2] = h_; \
            al[q >> 1][(q & 1) * 4 + e2] = (h16)(f_ - (float)h_); } } } while (0)

#define MFMAC(buf) do { _Pragma("unroll") for (int kh = 0; kh < 2; kh++) { \
        h8 b0 = *(const h8*)(lds + (buf) * 8192 + kh * 4096 + (wc * 2 + 0) * 1024 + rdo); \
        h8 b1 = *(const h8*)(lds + (buf) * 8192 + kh * 4096 + (wc * 2 + 1) * 1024 + rdo); \
        acc[0] = __builtin_amdgcn_mfma_f32_32x32x16_f16(ah[kh], b0, acc[0], 0, 0, 0); \
        acc[1] = __builtin_amdgcn_mfma_f32_32x32x16_f16(ah[kh], b1, acc[1], 0, 0, 0); \
        acc[0] = __builtin_amdgcn_mfma_f32_32x32x16_f16(al[kh], b0, acc[0], 0, 0, 0); \
        acc[1] = __builtin_amdgcn_mfma_f32_32x32x16_f16(al[kh], b1, acc[1], 0, 0, 0); } } while (0)

#define ITER(C, BUF, XS) do { \
        if ((C) + 1 < NCH) STW(1 - (BUF), (C) + 1); \
        CONVX(XS); \
        if ((C) + 2 < NCH) LOADX(XS, (C) + 2); \
        MFMAC(BUF); \
        if ((C) + 1 < NCH) { \
            if ((C) + 2 < NCH) asm volatile("s_waitcnt vmcnt(4)" ::: "memory"); \
            else               asm volatile("s_waitcnt vmcnt(0)" ::: "memory"); \
            __builtin_amdgcn_s_barrier(); \
            __builtin_amdgcn_sched_barrier(0); \
        } } while (0)

    // prologue: W(0) (oldest in FIFO), then x(0), x(1)
    STW(0, 0);
    LOADX(x0, 0);
    LOADX(x1, 1);
    asm volatile("s_waitcnt vmcnt(8)" ::: "memory");   // drain W(0) only
    __builtin_amdgcn_s_barrier();
    __builtin_amdgcn_sched_barrier(0);

    #pragma unroll 1
    for (int c = 0; c < NCH; c += 2) {
        ITER(c, 0, x0);
        ITER(c + 1, 1, x1);
    }

    // |x|^2 partial: oct halves hold disjoint k; only wc==0 waves write
    ssq += __shfl_xor(ssq, 32, 64);
    if (wc == 0 && l < 32) g_ssq[slice][t0 + wr * 32 + l] = ssq;

    // C write (32x32): row = (q&3)+8*(q>>2)+4*oct, col = wc*64 + j*32 + e5
    #pragma unroll
    for (int j = 0; j < 2; j++)
        #pragma unroll
        for (int q = 0; q < 16; q++) {
            int row = (q & 3) + 8 * (q >> 2) + 4 * oct;
            g_S[slice][t0 + wr * 32 + row][wc * 64 + j * 32 + e5] = acc[j][q];
        }

#undef STW
#undef LOADX
#undef CONVX
#undef MFMAC
#undef ITER
}

// ---------------- kernel 3: epilogue (reduce, argmax, softmax, fused hist) ----
// grid 256 x 128 threads; 64 tokens/block, 2 threads per token
__global__ __launch_bounds__(128) void k_epi() {
    __shared__ float gsm[128][65];
    __shared__ int hh[NE];
    const int tid = threadIdx.x;
    const int t = blockIdx.x * 64 + (tid >> 1);
    const int h = tid & 1;

    hh[tid] = 0;
    __syncthreads();

    float L[64];
    {
        const float* sp = &g_S[0][t][h * 64];
        #pragma unroll
        for (int jj = 0; jj < 16; jj++) {
            f4 v = *(const f4*)(sp + jj * 4);
            L[jj*4+0] = v[0]; L[jj*4+1] = v[1]; L[jj*4+2] = v[2]; L[jj*4+3] = v[3];
        }
    }
    #pragma unroll
    for (int s = 1; s < NSPLIT; s++) {
        const float* sp = &g_S[s][t][h * 64];
        #pragma unroll
        for (int jj = 0; jj < 16; jj++) {
            f4 v = *(const f4*)(sp + jj * 4);
            L[jj*4+0] += v[0]; L[jj*4+1] += v[1]; L[jj*4+2] += v[2]; L[jj*4+3] += v[3];
        }
    }
    float n2 = g_ssq[0][t] + g_ssq[1][t] + g_ssq[2][t] + g_ssq[3][t];
    float scl = 1.0f / fmaxf(sqrtf(n2), 1e-4f);

    float m1 = -1e30f, m2 = -1e30f;
    int a1 = h * 64;
    #pragma unroll
    for (int j = 0; j < 64; j++) {
        float v = L[j] * scl;
        L[j] = v;
        if (v > m1) { m2 = m1; m1 = v; a1 = h * 64 + j; }
        else if (v > m2) m2 = v;
    }
    float m1o = __shfl_xor(m1, 1, 64);
    int   a1o = __shfl_xor(a1, 1, 64);
    float m2o = __shfl_xor(m2, 1, 64);
    float m2g = fmaxf(fmaxf(m2, m2o), fminf(m1, m1o));
    float m1g; int a1g;
    if (m1o > m1 || (m1o == m1 && a1o < a1)) { m1g = m1o; a1g = a1o; }
    else { m1g = m1; a1g = a1; }

    if (h == 0) {
        g_tte[t] = a1g;
        atomicAdd(&hh[a1g], 1);
        if (m1g - m2g < TAU) {               // near-tie -> exact recheck
            int ix = atomicAdd(&g_cnt, 1);
            if (ix < FIXCAP) g_flag[ix] = t;
        }
    }

    float ssum = 0.f;
    #pragma unroll
    for (int j = 0; j < 64; j++) {
        float ex = __expf((L[j] - m1g) * INV_T);
        L[j] = ex;
        ssum += ex;
    }
    ssum += __shfl_xor(ssum, 1, 64);
    float inv = 1.0f / ssum;
    #pragma unroll
    for (int j = 0; j < 64; j++) gsm[tid][j] = L[j] * inv;
    __syncthreads();

    int e = tid;
    int col = e & 63, par = e >> 6;
    float s = 0.f;
    #pragma unroll 8
    for (int m = 0; m < 64; m++) s += gsm[2 * m + par][col];
    g_me[blockIdx.x][e] = s;
    g_hist[blockIdx.x][e] = hh[e];
}

// ---------------- kernel 4: exact fp32 recheck of near-tie tokens -------------
__global__ __launch_bounds__(64) void k_fix(const float* __restrict__ x) {
    int n = g_cnt;
    if (n > FIXCAP) n = FIXCAP;
    const int l = threadIdx.x;
    for (int i = blockIdx.x; i < n; i += gridDim.x) {
        int t = g_flag[i];
        float v0 = g_S[0][t][l], v1 = g_S[0][t][l + 64];
        #pragma unroll
        for (int s = 1; s < NSPLIT; s++) { v0 += g_S[s][t][l]; v1 += g_S[s][t][l + 64]; }
        float m = fmaxf(v0, v1);
        #pragma unroll
        for (int o = 1; o < 64; o <<= 1) m = fmaxf(m, __shfl_xor(m, o, 64));
        float n2 = g_ssq[0][t] + g_ssq[1][t] + g_ssq[2][t] + g_ssq[3][t];
        float thr = m - 1.5f * TAU * fmaxf(sqrtf(n2), 1e-4f);
        unsigned long long b0 = __ballot(v0 >= thr);
        unsigned long long b1 = __ballot(v1 >= thr);

        const float* xr = x + (size_t)t * D;
        float bm = -1e30f;
        int ba = 0;
        #pragma unroll 1
        for (int half = 0; half < 2; half++) {
            unsigned long long b = half ? b1 : b0;
            while (b) {
                int e = (__ffsll((long long)b) - 1) + half * 64;
                b &= b - 1;
                const float* wr = g_wgn + (size_t)e * D;
                float s = 0.f;
                #pragma unroll 4
                for (int c = 0; c < 16; c++) {
                    f4 xv = *(const f4*)(xr + c * 256 + l * 4);
                    f4 wv = *(const f4*)(wr + c * 256 + l * 4);
                    s = fmaf(xv[0], wv[0], s);
                    s = fmaf(xv[1], wv[1], s);
                    s = fmaf(xv[2], wv[2], s);
                    s = fmaf(xv[3], wv[3], s);
                }
                #pragma unroll
                for (int o = 1; o < 64; o <<= 1) s += __shfl_xor(s, o, 64);
                if (s > bm) { bm = s; ba = e; }   // ascending + strict > = first-index
            }
        }
        if (l == 0) {
            int old = g_tte[t];
            if (ba != old) {
                g_tte[t] = ba;
                atomicSub(&g_hist[t >> 6][old], 1);
                atomicAdd(&g_hist[t >> 6][ba], 1);
            }
        }
    }
}

// ---------------- kernel 5: scans + l_aux + splits ----------------------------
__global__ __launch_bounds__(128) void k_scan(float* __restrict__ out) {
    __shared__ int total[NE];
    __shared__ float me[NE];
    int e = threadIdx.x;
    int run = 0;
    #pragma unroll 8
    for (int c = 0; c < 256; c++) run += g_hist[c][e];
    total[e] = run;
    __syncthreads();
    int off = 0;
    for (int i = 0; i < e; i++) off += total[i];
    int p = off;
    for (int c = 0; c < 256; c++) { g_pos[c][e] = p; p += g_hist[c][e]; }
    float s = 0.f;
    #pragma unroll 8
    for (int b = 0; b < 256; b++) s += g_me[b][e];
    me[e] = s;
    __syncthreads();
    if (e == 0) {
        float acc = 0.f;
        for (int i = 0; i < NE; i++)
            acc += me[i] * ((float)total[i] * (1.0f / 16384.0f) + 1e-6f);
        out[0] = acc * 128.0f;   // l_aux
    }
    out[1 + NT + e]      = (float)total[e];   // input_splits
    out[1 + NT + NE + e] = (float)total[e];   // output_splits
}

// ---------------- kernel 6: stable placement (counting sort) ------------------
__global__ __launch_bounds__(64) void k_place(float* __restrict__ out) {
    __shared__ int arr[64];
    int tid = threadIdx.x;
    int c = blockIdx.x;
    int t = c * 64 + tid;
    int e = g_tte[t];
    arr[tid] = e;
    __syncthreads();
    int rank = 0;
    for (int j = 0; j < tid; j++) rank += (arr[j] == e) ? 1 : 0;
    out[1 + g_pos[c][e] + rank] = (float)t;
}

// ---------------- launcher ----------------------------------------------------
extern "C" void kernel_launch(void* const* d_in, const int* in_sizes, int n_in,
                              void* d_out, int out_size, void* d_ws, size_t ws_size,
                              hipStream_t stream) {
    const float* x  = (const float*)d_in[0];
    const float* wg = (const float*)d_in[1];
    // d_in[2] = gating_t: sigmoid(x/temp) is monotonic -> argmax unaffected
    float* out = (float*)d_out;

    k_prep<<<NE, 256, 0, stream>>>(wg);
    k_mfma<<<(NT / BMT) * NSPLIT, 512, 0, stream>>>(x);
    k_epi<<<256, 128, 0, stream>>>();
    k_fix<<<1024, 64, 0, stream>>>(x);
    k_scan<<<1, 128, 0, stream>>>(out);
    k_place<<<256, 64, 0, stream>>>(out);
}

// Round 9
// 120.361 us; speedup vs baseline: 1.1723x; 1.1723x over previous
//
#include <hip/hip_runtime.h>
#include <math.h>

#define NT 16384
#define D 4096
#define NE 128
#define KS 1024           // K per wave (block-internal split-K across 4 waves)
#define NCH 32            // chunks per wave (BK=32)
#define BMT 32            // tokens per block
#define INV_T (1.0f / 0.07f)
#define TAU 4e-5f
#define FIXCAP 16384

typedef _Float16 h16;
typedef _Float16 h8 __attribute__((ext_vector_type(8)));
typedef _Float16 h4 __attribute__((ext_vector_type(4)));
typedef float f4 __attribute__((ext_vector_type(4)));
typedef float f16v __attribute__((ext_vector_type(16)));

// ---- static device scratch (fully rewritten each call) ----
__device__ float g_wgn[NE * D];          // normalized W fp32 (fixup)
// W hi-plane packed: [kslice][chunk][kh][g][oct][e32][8 h16] -> 8KB per (slice,chunk)
__device__ __align__(16) h16 g_wpk[NE * D];
__device__ int   g_tte[NT];
__device__ int   g_cnt;
__device__ int   g_flag[FIXCAP];
__device__ float g_cand[FIXCAP][NE];     // cosine logits of flagged tokens
__device__ float g_me[NT / BMT][NE];     // per-block softmax column sums (512 rows)
__device__ int   g_hist[256][NE];        // per-64-token-chunk histograms (atomic)
__device__ int   g_pos[256][NE];

// ---------------- kernel 1: normalize W + fp16 hi split + pack + hist zero ----
__global__ __launch_bounds__(256) void k_prep(const float* __restrict__ wg) {
    int e = blockIdx.x;
    int tid = threadIdx.x;
    if (e == 0 && tid == 0) g_cnt = 0;
    g_hist[e * 2 + (tid >> 7)][tid & 127] = 0;   // 128 blocks x 256 thr = all 256x128
    const f4* row = (const f4*)(wg + (size_t)e * D);
    float ss = 0.f;
    f4 v[4];
    #pragma unroll
    for (int c = 0; c < 4; c++) {
        v[c] = row[tid + 256 * c];
        ss += v[c][0]*v[c][0] + v[c][1]*v[c][1] + v[c][2]*v[c][2] + v[c][3]*v[c][3];
    }
    __shared__ float red[4];
    #pragma unroll
    for (int o = 32; o > 0; o >>= 1) ss += __shfl_xor(ss, o, 64);
    if ((tid & 63) == 0) red[tid >> 6] = ss;
    __syncthreads();
    float den = fmaxf(sqrtf(red[0] + red[1] + red[2] + red[3]), 1e-4f);
    int g = e >> 5, e5 = e & 31;
    #pragma unroll
    for (int cc = 0; cc < 4; cc++) {
        int k0 = (tid + 256 * cc) * 4;
        f4 wn;
        h4 hi;
        #pragma unroll
        for (int k = 0; k < 4; k++) {
            wn[k] = v[cc][k] / den;
            hi[k] = (h16)wn[k];
        }
        *(f4*)(g_wgn + (size_t)e * D + k0) = wn;
        // pack: k -> slice=k>>10, kc=(k>>5)&31, kh=(k>>4)&1, oct=(k>>3)&1, d=k&7
        int slice = k0 >> 10, kc = (k0 >> 5) & 31;
        int kh = (k0 >> 4) & 1, oct = (k0 >> 3) & 1;
        size_t off = (size_t)(slice * 32 + kc) * 8192 + (size_t)kh * 4096
                   + (size_t)g * 1024 + (size_t)oct * 512 + (size_t)e5 * 16
                   + (size_t)(k0 & 7) * 2;
        *(h4*)((char*)g_wpk + off) = hi;
    }
}

// ---------------- kernel 2: fused fp16x2 32x32x16 GEMM + epilogue -------------
// grid 512 (2 blk/CU), 256 thr = 4 waves. Block: 32 tokens x 128 experts x K=4096.
// Wave w owns K-quarter [w*1024, +1024). NO barriers / NO LDS in the K-loop:
// W B-frags load L2->VGPR directly (W-hi is 1MB, L2-resident); x global->reg.
__global__ __launch_bounds__(256, 2) void k_gemm(const float* __restrict__ x) {
    __shared__ float red[2][32][128];    // 32KB: pairwise K-slice reduction + gates
    __shared__ float ssqr[4][32];
    __shared__ int hh[NE];

    const int tid = threadIdx.x;
    const int t0 = blockIdx.x * BMT;
    const int w = tid >> 6, l = tid & 63;
    const int e5 = l & 31, oct = l >> 5;

    const char* wbase = (const char*)g_wpk + (size_t)w * 32 * 8192
                        + (size_t)oct * 512 + (size_t)e5 * 16;
    const float* xb = x + (size_t)(t0 + e5) * D + w * KS + oct * 8;

    if (tid < NE) hh[tid] = 0;

    f16v acc[4];
    acc[0] = (f16v)0.0f; acc[1] = (f16v)0.0f;
    acc[2] = (f16v)0.0f; acc[3] = (f16v)0.0f;
    float ssq = 0.f;
    f4 x0[4], x1[4];
    h8 ah[2], al[2], bA[8], bB[8];

#define LOADW(B_, c) do { _Pragma("unroll") for (int j = 0; j < 8; j++) \
        B_[j] = *(const h8*)(wbase + (size_t)(c) * 8192 + (j >> 2) * 4096 + (j & 3) * 1024); } while (0)

#define LOADX(X, c) do { \
        X[0] = *(const f4*)(xb + (c) * 32); \
        X[1] = *(const f4*)(xb + (c) * 32 + 4); \
        X[2] = *(const f4*)(xb + (c) * 32 + 16); \
        X[3] = *(const f4*)(xb + (c) * 32 + 20); } while (0)

#define CONVX(X) do { _Pragma("unroll") for (int q = 0; q < 4; q++) { \
        _Pragma("unroll") for (int e2 = 0; e2 < 4; e2++) { \
            float f_ = X[q][e2]; \
            ssq += f_ * f_; \
            h16 h_ = (h16)f_; \
            ah[q >> 1][(q & 1) * 4 + e2] = h_; \
            al[q >> 1][(q & 1) * 4 + e2] = (h16)(f_ - (float)h_); } } } while (0)

#define MFMAC(B_) do { _Pragma("unroll") for (int kh = 0; kh < 2; kh++) \
        _Pragma("unroll") for (int g = 0; g < 4; g++) { \
            acc[g] = __builtin_amdgcn_mfma_f32_32x32x16_f16(ah[kh], B_[kh * 4 + g], acc[g], 0, 0, 0); \
            acc[g] = __builtin_amdgcn_mfma_f32_32x32x16_f16(al[kh], B_[kh * 4 + g], acc[g], 0, 0, 0); } } while (0)

    LOADW(bA, 0);
    LOADX(x0, 0);
    LOADX(x1, 1);
    #pragma unroll 1
    for (int c = 0; c < NCH; c += 2) {
        if (c + 1 < NCH) LOADW(bB, c + 1);
        CONVX(x0);
        if (c + 2 < NCH) LOADX(x0, c + 2);
        MFMAC(bA);
        if (c + 2 < NCH) LOADW(bA, c + 2);
        CONVX(x1);
        if (c + 3 < NCH) LOADX(x1, c + 3);
        MFMAC(bB);
    }

    // per-token |x|^2 for this K-quarter
    ssq += __shfl_xor(ssq, 32, 64);
    if (l < 32) ssqr[w][l] = ssq;

    // deterministic cross-wave (K-slice) reduction via LDS, 2 rounds
#define ACCST(H) do { _Pragma("unroll") for (int g = 0; g < 4; g++) \
        _Pragma("unroll") for (int q = 0; q < 16; q++) \
            red[H][(q & 3) + 8 * (q >> 2) + 4 * oct][g * 32 + e5] = acc[g][q]; } while (0)
#define ACCADD(H) do { _Pragma("unroll") for (int g = 0; g < 4; g++) \
        _Pragma("unroll") for (int q = 0; q < 16; q++) \
            acc[g][q] += red[H][(q & 3) + 8 * (q >> 2) + 4 * oct][g * 32 + e5]; } while (0)

    __syncthreads();
    if (w == 1) ACCST(0);
    if (w == 3) ACCST(1);
    __syncthreads();
    if (w == 0) ACCADD(0);
    if (w == 2) ACCADD(1);
    __syncthreads();
    if (w == 2) ACCST(1);
    __syncthreads();
    if (w == 0) { ACCADD(1); ACCST(0); }   // full raw dots -> red[0]
    __syncthreads();

    // ---- epilogue: 8 threads per token, 16 experts each ----
    const int tl = tid >> 3, g8 = tid & 7, e0 = g8 * 16;
    float n2 = ssqr[0][tl] + ssqr[1][tl] + ssqr[2][tl] + ssqr[3][tl];
    float scl = 1.0f / fmaxf(sqrtf(n2), 1e-4f);
    float v[16];
    #pragma unroll
    for (int k = 0; k < 16; k += 4) *(f4*)&v[k] = *(const f4*)&red[0][tl][e0 + k];

    float m1 = -1e30f, m2 = -1e30f;
    int a1 = e0;
    #pragma unroll
    for (int k = 0; k < 16; k++) {
        float cv = v[k] * scl;
        v[k] = cv;
        if (cv > m1) { m2 = m1; m1 = cv; a1 = e0 + k; }
        else if (cv > m2) m2 = cv;
    }
    #pragma unroll
    for (int o = 1; o < 8; o <<= 1) {
        float m1o = __shfl_xor(m1, o, 64);
        int   a1o = __shfl_xor(a1, o, 64);
        float m2o = __shfl_xor(m2, o, 64);
        m2 = fmaxf(fmaxf(m2, m2o), fminf(m1, m1o));
        if (m1o > m1 || (m1o == m1 && a1o < a1)) { m1 = m1o; a1 = a1o; }
    }
    const int tg = t0 + tl;
    if (g8 == 0) {
        g_tte[tg] = a1;
        atomicAdd(&hh[a1], 1);
    }
    if (m1 - m2 < TAU) {                   // near-tie -> exact recheck later
        int ix = 0;
        if (g8 == 0) ix = atomicAdd(&g_cnt, 1);
        ix = __shfl(ix, l & ~7, 64);
        if (ix < FIXCAP) {
            if (g8 == 0) g_flag[ix] = tg;
            #pragma unroll
            for (int k = 0; k < 16; k += 4) {
                f4 t4;
                t4[0] = v[k]; t4[1] = v[k + 1]; t4[2] = v[k + 2]; t4[3] = v[k + 3];
                *(f4*)&g_cand[ix][e0 + k] = t4;
            }
        }
    }

    // softmax(cos/0.07)
    float ssum = 0.f;
    #pragma unroll
    for (int k = 0; k < 16; k++) {
        float ex = __expf((v[k] - m1) * INV_T);
        v[k] = ex;
        ssum += ex;
    }
    ssum += __shfl_xor(ssum, 1, 64);
    ssum += __shfl_xor(ssum, 2, 64);
    ssum += __shfl_xor(ssum, 4, 64);
    float inv = 1.0f / ssum;
    #pragma unroll
    for (int k = 0; k < 16; k += 4) {
        f4 t4;
        t4[0] = v[k] * inv; t4[1] = v[k + 1] * inv;
        t4[2] = v[k + 2] * inv; t4[3] = v[k + 3] * inv;
        *(f4*)&red[1][tl][e0 + k] = t4;
    }
    __syncthreads();
    if (tid < NE) {
        float s = 0.f;
        #pragma unroll 8
        for (int r = 0; r < 32; r++) s += red[1][r][tid];
        g_me[blockIdx.x][tid] = s;
        atomicAdd(&g_hist[blockIdx.x >> 1][tid], hh[tid]);
    }

#undef LOADW
#undef LOADX
#undef CONVX
#undef MFMAC
#undef ACCST
#undef ACCADD
}

// ---------------- kernel 3: exact fp32 recheck of near-tie tokens -------------
// Candidates = experts within TAU (cosine units) of approx max (from g_cand);
// exact fp32 dots only for those, ascending + strict > = first-index tie-break.
__global__ __launch_bounds__(64) void k_fix(const float* __restrict__ x) {
    int n = g_cnt;
    if (n > FIXCAP) n = FIXCAP;
    const int l = threadIdx.x;
    for (int i = blockIdx.x; i < n; i += gridDim.x) {
        int t = g_flag[i];
        float c0 = g_cand[i][l], c1 = g_cand[i][l + 64];
        float m = fmaxf(c0, c1);
        #pragma unroll
        for (int o = 1; o < 64; o <<= 1) m = fmaxf(m, __shfl_xor(m, o, 64));
        float thr = m - TAU;
        unsigned long long b0 = __ballot(c0 >= thr);
        unsigned long long b1 = __ballot(c1 >= thr);

        const float* xr = x + (size_t)t * D;
        float bm = -1e30f;
        int ba = 0;
        #pragma unroll 1
        for (int half = 0; half < 2; half++) {
            unsigned long long b = half ? b1 : b0;
            while (b) {
                int e = (__ffsll((long long)b) - 1) + half * 64;
                b &= b - 1;
                const float* wr = g_wgn + (size_t)e * D;
                float s = 0.f;
                #pragma unroll 4
                for (int c = 0; c < 16; c++) {
                    f4 xv = *(const f4*)(xr + c * 256 + l * 4);
                    f4 wv = *(const f4*)(wr + c * 256 + l * 4);
                    s = fmaf(xv[0], wv[0], s);
                    s = fmaf(xv[1], wv[1], s);
                    s = fmaf(xv[2], wv[2], s);
                    s = fmaf(xv[3], wv[3], s);
                }
                #pragma unroll
                for (int o = 1; o < 64; o <<= 1) s += __shfl_xor(s, o, 64);
                if (s > bm) { bm = s; ba = e; }
            }
        }
        if (l == 0) {
            int old = g_tte[t];
            if (ba != old) {
                g_tte[t] = ba;
                atomicSub(&g_hist[t >> 6][old], 1);
                atomicAdd(&g_hist[t >> 6][ba], 1);
            }
        }
    }
}

// ---------------- kernel 4: scans + l_aux + splits ----------------------------
__global__ __launch_bounds__(128) void k_scan(float* __restrict__ out) {
    __shared__ int total[NE];
    __shared__ float me[NE];
    int e = threadIdx.x;
    int run = 0;
    #pragma unroll 8
    for (int c = 0; c < 256; c++) run += g_hist[c][e];
    total[e] = run;
    __syncthreads();
    int off = 0;
    for (int i = 0; i < e; i++) off += total[i];
    int p = off;
    for (int c = 0; c < 256; c++) { g_pos[c][e] = p; p += g_hist[c][e]; }
    float s = 0.f;
    #pragma unroll 8
    for (int b = 0; b < NT / BMT; b++) s += g_me[b][e];
    me[e] = s;
    __syncthreads();
    if (e == 0) {
        float acc = 0.f;
        for (int i = 0; i < NE; i++)
            acc += me[i] * ((float)total[i] * (1.0f / 16384.0f) + 1e-6f);
        out[0] = acc * 128.0f;   // l_aux
    }
    out[1 + NT + e]      = (float)total[e];   // input_splits
    out[1 + NT + NE + e] = (float)total[e];   // output_splits
}

// ---------------- kernel 5: stable placement (counting sort) ------------------
__global__ __launch_bounds__(64) void k_place(float* __restrict__ out) {
    __shared__ int arr[64];
    int tid = threadIdx.x;
    int c = blockIdx.x;
    int t = c * 64 + tid;
    int e = g_tte[t];
    arr[tid] = e;
    __syncthreads();
    int rank = 0;
    for (int j = 0; j < tid; j++) rank += (arr[j] == e) ? 1 : 0;
    out[1 + g_pos[c][e] + rank] = (float)t;
}

// ---------------- launcher ----------------------------------------------------
extern "C" void kernel_launch(void* const* d_in, const int* in_sizes, int n_in,
                              void* d_out, int out_size, void* d_ws, size_t ws_size,
                              hipStream_t stream) {
    const float* x  = (const float*)d_in[0];
    const float* wg = (const float*)d_in[1];
    // d_in[2] = gating_t: sigmoid(x/temp) is monotonic -> argmax unaffected
    float* out = (float*)d_out;

    k_prep<<<NE, 256, 0, stream>>>(wg);
    k_gemm<<<NT / BMT, 256, 0, stream>>>(x);
    k_fix<<<1024, 64, 0, stream>>>(x);
    k_scan<<<1, 128, 0, stream>>>(out);
    k_place<<<256, 64, 0, stream>>>(out);
}